// Round 1
// baseline (1174.651 us; speedup 1.0000x reference)
//
#include <hip/hip_runtime.h>
#include <cstdint>
#include <cmath>

// Shapes: B=16, Cb=256, H=W=128 -> h2=w2=64. hid=512. Cs=512.
// hf tokens: 32x32=1024/batch/band, 3 bands -> 49152 tokens, dim 256.
// lf tokens: 16x16=256/batch -> 4096 tokens, dim 256 (after low_w proj).

// ---------------------------------------------------------------- K1: Haar |band| 2x2-mean tokens
// z layout: [band(3)][b*256+c][1024 tokens], token t = py*32+px
__global__ __launch_bounds__(256)
void k_haar_tokens(const float* __restrict__ xb, float* __restrict__ z)
{
    const int bc = blockIdx.x;            // b*256 + c
    const int px  = threadIdx.x & 31;
    const int py0 = threadIdx.x >> 5;     // [0,8)
    const float* base = xb + (size_t)bc * (128 * 128);
#pragma unroll
    for (int s = 0; s < 4; ++s) {
        const int py = py0 + 8 * s;       // [0,32)
        const float* p = base + (4 * py) * 128 + 4 * px;
        const float4 r0 = *(const float4*)(p);
        const float4 r1 = *(const float4*)(p + 128);
        const float4 r2 = *(const float4*)(p + 256);
        const float4 r3 = *(const float4*)(p + 384);
        float zh = 0.f, zv = 0.f, zd = 0.f;
        {   // half-res pos (2py, 2px)
            const float p00 = r0.x, p01 = r0.y, p10 = r1.x, p11 = r1.y;
            zh += fabsf(p00 - p01 + p10 - p11);
            zv += fabsf(p00 + p01 - p10 - p11);
            zd += fabsf(p00 - p01 - p10 + p11);
        }
        {   // (2py, 2px+1)
            const float p00 = r0.z, p01 = r0.w, p10 = r1.z, p11 = r1.w;
            zh += fabsf(p00 - p01 + p10 - p11);
            zv += fabsf(p00 + p01 - p10 - p11);
            zd += fabsf(p00 - p01 - p10 + p11);
        }
        {   // (2py+1, 2px)
            const float p00 = r2.x, p01 = r2.y, p10 = r3.x, p11 = r3.y;
            zh += fabsf(p00 - p01 + p10 - p11);
            zv += fabsf(p00 + p01 - p10 - p11);
            zd += fabsf(p00 - p01 - p10 + p11);
        }
        {   // (2py+1, 2px+1)
            const float p00 = r2.z, p01 = r2.w, p10 = r3.z, p11 = r3.w;
            zh += fabsf(p00 - p01 + p10 - p11);
            zv += fabsf(p00 + p01 - p10 - p11);
            zd += fabsf(p00 - p01 - p10 + p11);
        }
        // band scale 0.25 and mean over 4 positions (0.25)
        const float sc = 0.0625f;
        const int t = py * 32 + px;
        z[(size_t)(0 * 4096 + bc) * 1024 + t] = zh * sc;
        z[(size_t)(1 * 4096 + bc) * 1024 + t] = zv * sc;
        z[(size_t)(2 * 4096 + bc) * 1024 + t] = zd * sc;
    }
}

// ---------------------------------------------------------------- K2: 4x4 mean pool of x_small
// sp layout: [b*512+s][256 tokens], token = py*16+px
__global__ __launch_bounds__(256)
void k_pool_small(const float* __restrict__ xs, float* __restrict__ sp)
{
    const int bs = blockIdx.x;            // b*512 + s
    const int px = threadIdx.x & 15;
    const int py = threadIdx.x >> 4;
    const float* p = xs + (size_t)bs * 4096 + (4 * py) * 64 + 4 * px;
    float s = 0.f;
#pragma unroll
    for (int r = 0; r < 4; ++r) {
        const float4 v = *(const float4*)(p + 64 * r);
        s += v.x + v.y + v.z + v.w;
    }
    sp[(size_t)bs * 256 + threadIdx.x] = s * 0.0625f;
}

// ---------------------------------------------------------------- K3: fused hf MLP + cosine head
// grid = 3*16*64 blocks; block handles 16 tokens. blockIdx = bb*64 + tile, bb = band*16+b.
__global__ __launch_bounds__(256, 2)
void k_mlp_high(const float* __restrict__ z,
                const float* __restrict__ w1, const float* __restrict__ b1,
                const float* __restrict__ lnw, const float* __restrict__ lnb,
                const float* __restrict__ w2, const float* __restrict__ b2,
                const float* __restrict__ prompt,
                float* __restrict__ alpha)
{
    __shared__ float zt[256 * 16];        // [k][t]  (also reused for q[d][t])
    __shared__ float Hl[512 * 20];        // [j][t], row stride 20 (16B aligned, bank spread)
    __shared__ float mu_s[16], rs_s[16];
    const int tid  = threadIdx.x;
    const int tile = blockIdx.x & 63;
    const int bb   = blockIdx.x >> 6;
    const int t0   = tile * 16;

    {   // stage z tile: thread = input channel
        const float* src = z + ((size_t)bb * 256 + tid) * 1024 + t0;
        *(float4*)&zt[tid * 16 + 0]  = *(const float4*)(src + 0);
        *(float4*)&zt[tid * 16 + 4]  = *(const float4*)(src + 4);
        *(float4*)&zt[tid * 16 + 8]  = *(const float4*)(src + 8);
        *(float4*)&zt[tid * 16 + 12] = *(const float4*)(src + 12);
    }
    __syncthreads();

    // ---- layer 1: thread owns hidden cols j0, j0+1
    const int j0 = tid * 2;
    float acc0[16], acc1[16];
#pragma unroll
    for (int t = 0; t < 16; ++t) { acc0[t] = 0.f; acc1[t] = 0.f; }
    for (int k = 0; k < 256; ++k) {
        const float2 w = *(const float2*)(w1 + (size_t)k * 512 + j0);
        float zv[16];
        *(float4*)&zv[0]  = *(const float4*)&zt[k * 16 + 0];
        *(float4*)&zv[4]  = *(const float4*)&zt[k * 16 + 4];
        *(float4*)&zv[8]  = *(const float4*)&zt[k * 16 + 8];
        *(float4*)&zv[12] = *(const float4*)&zt[k * 16 + 12];
#pragma unroll
        for (int t = 0; t < 16; ++t) {
            acc0[t] = fmaf(zv[t], w.x, acc0[t]);
            acc1[t] = fmaf(zv[t], w.y, acc1[t]);
        }
    }
    {
        const float bb0 = b1[j0], bb1 = b1[j0 + 1];
#pragma unroll
        for (int t4 = 0; t4 < 16; t4 += 4) {
            *(float4*)&Hl[j0 * 20 + t4] =
                make_float4(acc0[t4] + bb0, acc0[t4 + 1] + bb0, acc0[t4 + 2] + bb0, acc0[t4 + 3] + bb0);
            *(float4*)&Hl[(j0 + 1) * 20 + t4] =
                make_float4(acc1[t4] + bb1, acc1[t4 + 1] + bb1, acc1[t4 + 2] + bb1, acc1[t4 + 3] + bb1);
        }
    }
    __syncthreads();

    // ---- LN stats: 16 threads per token
    {
        const int t = tid >> 4, g = tid & 15;
        float s = 0.f, ss = 0.f;
        for (int j = g; j < 512; j += 16) {
            const float v = Hl[j * 20 + t];
            s += v; ss = fmaf(v, v, ss);
        }
#pragma unroll
        for (int m = 1; m < 16; m <<= 1) { s += __shfl_xor(s, m); ss += __shfl_xor(ss, m); }
        if (g == 0) {
            const float mu  = s * (1.f / 512.f);
            const float var = ss * (1.f / 512.f) - mu * mu;
            mu_s[t] = mu;
            rs_s[t] = rsqrtf(var + 1e-5f);
        }
    }
    __syncthreads();

    // ---- LN apply in-place on owned rows
    {
        const float lw0 = lnw[j0], lb0 = lnb[j0], lw1 = lnw[j0 + 1], lb1 = lnb[j0 + 1];
#pragma unroll
        for (int t = 0; t < 16; ++t) {
            const float m = mu_s[t], r = rs_s[t];
            Hl[j0 * 20 + t]       = (Hl[j0 * 20 + t] - m) * r * lw0 + lb0;
            Hl[(j0 + 1) * 20 + t] = (Hl[(j0 + 1) * 20 + t] - m) * r * lw1 + lb1;
        }
    }
    __syncthreads();

    // ---- layer 2: thread owns out col d = tid
    float acc2[16];
#pragma unroll
    for (int t = 0; t < 16; ++t) acc2[t] = 0.f;
    for (int k = 0; k < 512; ++k) {
        const float w = w2[(size_t)k * 256 + tid];
        float hv[16];
        *(float4*)&hv[0]  = *(const float4*)&Hl[k * 20 + 0];
        *(float4*)&hv[4]  = *(const float4*)&Hl[k * 20 + 4];
        *(float4*)&hv[8]  = *(const float4*)&Hl[k * 20 + 8];
        *(float4*)&hv[12] = *(const float4*)&Hl[k * 20 + 12];
#pragma unroll
        for (int t = 0; t < 16; ++t) acc2[t] = fmaf(hv[t], w, acc2[t]);
    }
    {   // write q into zt (all zt readers finished at the post-layer1 barrier)
        const float b2v = b2[tid];
#pragma unroll
        for (int t4 = 0; t4 < 16; t4 += 4)
            *(float4*)&zt[tid * 16 + t4] =
                make_float4(acc2[t4] + b2v, acc2[t4 + 1] + b2v, acc2[t4 + 2] + b2v, acc2[t4 + 3] + b2v);
    }
    __syncthreads();

    // ---- cosine head
    {
        const int t = tid >> 4, g = tid & 15;
        float dot = 0.f, nq2 = 0.f, pp = 0.f;
        for (int d = g; d < 256; d += 16) {
            const float q  = zt[d * 16 + t];
            const float pr = prompt[d];
            dot = fmaf(q, pr, dot);
            nq2 = fmaf(q, q, nq2);
            pp  = fmaf(pr, pr, pp);
        }
#pragma unroll
        for (int m = 1; m < 16; m <<= 1) {
            dot += __shfl_xor(dot, m); nq2 += __shfl_xor(nq2, m); pp += __shfl_xor(pp, m);
        }
        if (g == 0) {
            const float nq  = fmaxf(sqrtf(nq2), 1e-8f);
            const float npr = fmaxf(sqrtf(pp), 1e-8f);
            const float sim = dot / (nq * npr);
            alpha[(size_t)bb * 1024 + t0 + t] = fmaxf(sim, 0.f);
        }
    }
}

// ---------------------------------------------------------------- K4: fused low path: pool-proj + MLP + sigmoid
// grid = 16*16 blocks; block = 16 tokens. gate layout: [b*256+d][256 tokens]
__global__ __launch_bounds__(256, 2)
void k_mlp_low(const float* __restrict__ sp,
               const float* __restrict__ lw_, const float* __restrict__ lb_,
               const float* __restrict__ w1, const float* __restrict__ b1,
               const float* __restrict__ lnw, const float* __restrict__ lnb,
               const float* __restrict__ w2, const float* __restrict__ b2,
               float* __restrict__ gate)
{
    __shared__ float zt[256 * 16];
    __shared__ float Hl[512 * 20];
    __shared__ float mu_s[16], rs_s[16];
    const int tid  = threadIdx.x;
    const int tile = blockIdx.x & 15;
    const int b    = blockIdx.x >> 4;
    const int t0   = tile * 16;

    // stage s_pool tile (512 x 16) into Hl
#pragma unroll
    for (int hh = 0; hh < 2; ++hh) {
        const int s = tid + hh * 256;
        const float* src = sp + ((size_t)b * 512 + s) * 256 + t0;
        *(float4*)&Hl[s * 20 + 0]  = *(const float4*)(src + 0);
        *(float4*)&Hl[s * 20 + 4]  = *(const float4*)(src + 4);
        *(float4*)&Hl[s * 20 + 8]  = *(const float4*)(src + 8);
        *(float4*)&Hl[s * 20 + 12] = *(const float4*)(src + 12);
    }
    __syncthreads();

    // pre-layer: k_tok col c = tid  (k_tok = pool(x_small) @ low_w + low_b)
    {
        float acc[16];
#pragma unroll
        for (int t = 0; t < 16; ++t) acc[t] = 0.f;
        for (int s = 0; s < 512; ++s) {
            const float w = lw_[(size_t)s * 256 + tid];
            float hv[16];
            *(float4*)&hv[0]  = *(const float4*)&Hl[s * 20 + 0];
            *(float4*)&hv[4]  = *(const float4*)&Hl[s * 20 + 4];
            *(float4*)&hv[8]  = *(const float4*)&Hl[s * 20 + 8];
            *(float4*)&hv[12] = *(const float4*)&Hl[s * 20 + 12];
#pragma unroll
            for (int t = 0; t < 16; ++t) acc[t] = fmaf(hv[t], w, acc[t]);
        }
        const float lbv = lb_[tid];
#pragma unroll
        for (int t4 = 0; t4 < 16; t4 += 4)
            *(float4*)&zt[tid * 16 + t4] =
                make_float4(acc[t4] + lbv, acc[t4 + 1] + lbv, acc[t4 + 2] + lbv, acc[t4 + 3] + lbv);
    }
    __syncthreads();

    // layer 1
    const int j0 = tid * 2;
    float acc0[16], acc1[16];
#pragma unroll
    for (int t = 0; t < 16; ++t) { acc0[t] = 0.f; acc1[t] = 0.f; }
    for (int k = 0; k < 256; ++k) {
        const float2 w = *(const float2*)(w1 + (size_t)k * 512 + j0);
        float zv[16];
        *(float4*)&zv[0]  = *(const float4*)&zt[k * 16 + 0];
        *(float4*)&zv[4]  = *(const float4*)&zt[k * 16 + 4];
        *(float4*)&zv[8]  = *(const float4*)&zt[k * 16 + 8];
        *(float4*)&zv[12] = *(const float4*)&zt[k * 16 + 12];
#pragma unroll
        for (int t = 0; t < 16; ++t) {
            acc0[t] = fmaf(zv[t], w.x, acc0[t]);
            acc1[t] = fmaf(zv[t], w.y, acc1[t]);
        }
    }
    {
        const float bb0 = b1[j0], bb1 = b1[j0 + 1];
#pragma unroll
        for (int t4 = 0; t4 < 16; t4 += 4) {
            *(float4*)&Hl[j0 * 20 + t4] =
                make_float4(acc0[t4] + bb0, acc0[t4 + 1] + bb0, acc0[t4 + 2] + bb0, acc0[t4 + 3] + bb0);
            *(float4*)&Hl[(j0 + 1) * 20 + t4] =
                make_float4(acc1[t4] + bb1, acc1[t4 + 1] + bb1, acc1[t4 + 2] + bb1, acc1[t4 + 3] + bb1);
        }
    }
    __syncthreads();

    // LN stats
    {
        const int t = tid >> 4, g = tid & 15;
        float s = 0.f, ss = 0.f;
        for (int j = g; j < 512; j += 16) {
            const float v = Hl[j * 20 + t];
            s += v; ss = fmaf(v, v, ss);
        }
#pragma unroll
        for (int m = 1; m < 16; m <<= 1) { s += __shfl_xor(s, m); ss += __shfl_xor(ss, m); }
        if (g == 0) {
            const float mu  = s * (1.f / 512.f);
            const float var = ss * (1.f / 512.f) - mu * mu;
            mu_s[t] = mu;
            rs_s[t] = rsqrtf(var + 1e-5f);
        }
    }
    __syncthreads();
    {
        const float lw0 = lnw[j0], lb0 = lnb[j0], lw1 = lnw[j0 + 1], lb1 = lnb[j0 + 1];
#pragma unroll
        for (int t = 0; t < 16; ++t) {
            const float m = mu_s[t], r = rs_s[t];
            Hl[j0 * 20 + t]       = (Hl[j0 * 20 + t] - m) * r * lw0 + lb0;
            Hl[(j0 + 1) * 20 + t] = (Hl[(j0 + 1) * 20 + t] - m) * r * lw1 + lb1;
        }
    }
    __syncthreads();

    // layer 2 + sigmoid -> gate
    {
        float acc2[16];
#pragma unroll
        for (int t = 0; t < 16; ++t) acc2[t] = 0.f;
        for (int k = 0; k < 512; ++k) {
            const float w = w2[(size_t)k * 256 + tid];
            float hv[16];
            *(float4*)&hv[0]  = *(const float4*)&Hl[k * 20 + 0];
            *(float4*)&hv[4]  = *(const float4*)&Hl[k * 20 + 4];
            *(float4*)&hv[8]  = *(const float4*)&Hl[k * 20 + 8];
            *(float4*)&hv[12] = *(const float4*)&Hl[k * 20 + 12];
#pragma unroll
            for (int t = 0; t < 16; ++t) acc2[t] = fmaf(hv[t], w, acc2[t]);
        }
        const float b2v = b2[tid];
        float* gbase = gate + ((size_t)b * 256 + tid) * 256 + t0;
#pragma unroll
        for (int t = 0; t < 16; ++t) {
            const float q = acc2[t] + b2v;
            gbase[t] = 1.f / (1.f + expf(-q));
        }
    }
}

// ---------------------------------------------------------------- K5: apply alpha/gate + inverse Haar
__global__ __launch_bounds__(256)
void k_final(const float* __restrict__ xb,
             const float* __restrict__ alpha,   // [3][16][1024]
             const float* __restrict__ gate,    // [16*256][256]
             float* __restrict__ out)
{
    const int bc    = blockIdx.x >> 3;     // b*256 + c
    const int ytile = blockIdx.x & 7;
    const int x2 = threadIdx.x & 31;            // half-res x pair index
    const int y  = ytile * 8 + (threadIdx.x >> 5);  // half-res row
    const int b  = bc >> 8;

    const float* p = xb + (size_t)bc * (128 * 128) + (2 * y) * 128 + 4 * x2;
    const float4 r0 = *(const float4*)(p);
    const float4 r1 = *(const float4*)(p + 128);

    const int th = (y >> 1) * 32 + x2;          // PH=2 token (same for both x positions)
    const float ah = alpha[(size_t)0 * 16384 + b * 1024 + th];
    const float av = alpha[(size_t)1 * 16384 + b * 1024 + th];
    const float ad = alpha[(size_t)2 * 16384 + b * 1024 + th];
    const float g  = gate[(size_t)bc * 256 + (y >> 2) * 16 + (x2 >> 1)];

    float4 o_top, o_bot;
    {   // half-res pos A: x = 2*x2
        const float p00 = r0.x, p01 = r0.y, p10 = r1.x, p11 = r1.y;
        const float a  = 0.25f * (p00 + p01 + p10 + p11) * g;
        const float hb = 0.25f * (p00 - p01 + p10 - p11) * ah;
        const float vb = 0.25f * (p00 + p01 - p10 - p11) * av;
        const float db = 0.25f * (p00 - p01 - p10 + p11) * ad;
        o_top.x = a + hb + vb + db;  o_top.y = a - hb + vb - db;
        o_bot.x = a + hb - vb - db;  o_bot.y = a - hb - vb + db;
    }
    {   // half-res pos B: x = 2*x2+1
        const float p00 = r0.z, p01 = r0.w, p10 = r1.z, p11 = r1.w;
        const float a  = 0.25f * (p00 + p01 + p10 + p11) * g;
        const float hb = 0.25f * (p00 - p01 + p10 - p11) * ah;
        const float vb = 0.25f * (p00 + p01 - p10 - p11) * av;
        const float db = 0.25f * (p00 - p01 - p10 + p11) * ad;
        o_top.z = a + hb + vb + db;  o_top.w = a - hb + vb - db;
        o_bot.z = a + hb - vb - db;  o_bot.w = a - hb - vb + db;
    }
    float* q = out + (size_t)bc * (128 * 128) + (2 * y) * 128 + 4 * x2;
    *(float4*)(q)       = o_top;
    *(float4*)(q + 128) = o_bot;
}

// ---------------------------------------------------------------- launch
extern "C" void kernel_launch(void* const* d_in, const int* in_sizes, int n_in,
                              void* d_out, int out_size, void* d_ws, size_t ws_size,
                              hipStream_t stream)
{
    (void)in_sizes; (void)n_in; (void)out_size; (void)ws_size;
    const float* x_big     = (const float*)d_in[0];
    const float* x_small   = (const float*)d_in[1];
    const float* hf_w1     = (const float*)d_in[2];
    const float* hf_b1     = (const float*)d_in[3];
    const float* hf_ln_w   = (const float*)d_in[4];
    const float* hf_ln_b   = (const float*)d_in[5];
    const float* hf_w2     = (const float*)d_in[6];
    const float* hf_b2     = (const float*)d_in[7];
    const float* hf_prompt = (const float*)d_in[8];
    const float* low_w     = (const float*)d_in[9];
    const float* low_b     = (const float*)d_in[10];
    const float* lf_w1     = (const float*)d_in[11];
    const float* lf_b1     = (const float*)d_in[12];
    const float* lf_ln_w   = (const float*)d_in[13];
    const float* lf_ln_b   = (const float*)d_in[14];
    const float* lf_w2     = (const float*)d_in[15];
    const float* lf_b2     = (const float*)d_in[16];
    float* out = (float*)d_out;

    float* ws    = (float*)d_ws;
    float* z     = ws;                               // 3*4096*1024   = 12,582,912 f
    float* sp    = z + (size_t)3 * 4096 * 1024;      // 16*512*256    =  2,097,152 f
    float* alpha = sp + (size_t)16 * 512 * 256;      // 3*16*1024     =     49,152 f
    float* gate  = alpha + (size_t)3 * 16 * 1024;    // 16*256*256    =  1,048,576 f

    k_haar_tokens<<<4096, 256, 0, stream>>>(x_big, z);
    k_pool_small <<<8192, 256, 0, stream>>>(x_small, sp);
    k_mlp_high   <<<3072, 256, 0, stream>>>(z, hf_w1, hf_b1, hf_ln_w, hf_ln_b,
                                            hf_w2, hf_b2, hf_prompt, alpha);
    k_mlp_low    <<<256, 256, 0, stream>>>(sp, low_w, low_b, lf_w1, lf_b1,
                                           lf_ln_w, lf_ln_b, lf_w2, lf_b2, gate);
    k_final      <<<32768, 256, 0, stream>>>(x_big, alpha, gate, out);
}